// Round 1
// baseline (545.353 us; speedup 1.0000x reference)
//
#include <hip/hip_runtime.h>
#include <hip/hip_bf16.h>

// Problem: GRUCell fused cell. B=16384, d=1024, 2d=2048.
//   inp  = LN(concat(x,h); g1,b1) * dm
//   gates= inp @ Wg + bg ; r=sig(gates[:, :d]); z=sig(gates[:, d:])
//   inp2 = LN(concat(x, h*r); g2,b2) * dm
//   u    = tanh(inp2 @ Wu + bu)
//   out  = h*z + (1-z)*u
//
// bf16 MFMA path (threshold is bf16-floor 8.4e-2).
// ws layout (bytes):
//   [0,            8388608)  WgT  bf16 [2048][2048]  (WgT[n][k] = Wg[k][n])
//   [8388608,     12582912)  WuT  bf16 [1024][2048]
//   [12582912,    79691776)  ln   bf16 [16384][2048] (reused for LN1 then LN2)
//   [79691776,   113246208)  hr   bf16 [16384][1024] (h * r)
// z (f32) is staged in d_out between GEMM1 and GEMM2 (each element read only
// by the thread that overwrites it).

#define BATCH 16384
#define DDIM  1024
#define TWOD  2048
#define LNEPS 1e-5f

typedef __bf16 bf16x8 __attribute__((ext_vector_type(8)));
typedef float  f32x4  __attribute__((ext_vector_type(4)));
typedef unsigned short ushort4v __attribute__((ext_vector_type(4)));

__device__ __forceinline__ unsigned short f2bf(float f) {
    unsigned int u = __builtin_bit_cast(unsigned int, f);
    u = (u + 0x7FFFu + ((u >> 16) & 1u)) >> 16;   // round-to-nearest-even
    return (unsigned short)u;
}
__device__ __forceinline__ float bf2f(unsigned short s) {
    unsigned int u = ((unsigned int)s) << 16;
    return __builtin_bit_cast(float, u);
}
__device__ __forceinline__ void gload16(const void* g, void* l) {
    __builtin_amdgcn_global_load_lds((__attribute__((address_space(1))) void*)(g),
                                     (__attribute__((address_space(3))) void*)(l),
                                     16u, 0, 0);
}

// ---------------- weight transpose + f32->bf16 cast ------------------------
// W: [K][N] f32 row-major  ->  WT: [N][K] bf16 row-major
__global__ __launch_bounds__(256) void wtrans(const float* __restrict__ W,
                                              unsigned short* __restrict__ WT,
                                              int K, int N) {
    __shared__ float tile[32][33];
    const int k0 = blockIdx.x * 32;
    const int n0 = blockIdx.y * 32;
    const int tx = threadIdx.x & 31;
    const int ty = threadIdx.x >> 5;   // 0..7
#pragma unroll
    for (int p = 0; p < 32; p += 8)
        tile[p + ty][tx] = W[(size_t)(k0 + p + ty) * N + n0 + tx];
    __syncthreads();
#pragma unroll
    for (int p = 0; p < 32; p += 8)
        WT[(size_t)(n0 + p + ty) * K + k0 + tx] = f2bf(tile[tx][p + ty]);
}

// ---------------- fused LayerNorm over concat(x, second) -------------------
// row = blockIdx.x; 256 threads; each thread handles 4 x-elems + 4 second-elems.
template <bool SECOND_BF16>
__global__ __launch_bounds__(256) void ln_kernel(const float* __restrict__ x,
                                                 const void* __restrict__ h2,
                                                 const float* __restrict__ g,
                                                 const float* __restrict__ bt,
                                                 const float* __restrict__ dm,
                                                 unsigned short* __restrict__ out) {
    const int row  = blockIdx.x;
    const int tid  = threadIdx.x;          // 0..255
    const int lane = tid & 63;
    const int w    = tid >> 6;

    const float4 xl = reinterpret_cast<const float4*>(x + (size_t)row * DDIM)[tid];
    float hv[4];
    if (SECOND_BF16) {
        const ushort4v hl = reinterpret_cast<const ushort4v*>(
            (const unsigned short*)h2 + (size_t)row * DDIM)[tid];
#pragma unroll
        for (int j = 0; j < 4; ++j) hv[j] = bf2f(hl[j]);
    } else {
        const float4 hl = reinterpret_cast<const float4*>(
            (const float*)h2 + (size_t)row * DDIM)[tid];
        hv[0] = hl.x; hv[1] = hl.y; hv[2] = hl.z; hv[3] = hl.w;
    }
    float xv[4] = {xl.x, xl.y, xl.z, xl.w};

    float s = 0.f, ss = 0.f;
#pragma unroll
    for (int j = 0; j < 4; ++j) { s += xv[j] + hv[j]; ss += xv[j]*xv[j] + hv[j]*hv[j]; }
#pragma unroll
    for (int o = 32; o; o >>= 1) { s += __shfl_xor(s, o); ss += __shfl_xor(ss, o); }
    __shared__ float red[8];
    if (lane == 0) { red[w] = s; red[4 + w] = ss; }
    __syncthreads();
    s  = red[0] + red[1] + red[2] + red[3];
    ss = red[4] + red[5] + red[6] + red[7];
    const float inv  = 1.0f / (float)TWOD;
    const float mu   = s * inv;
    const float var  = ss * inv - mu * mu;
    const float rstd = rsqrtf(var + LNEPS);

    // x half: columns 4*tid..4*tid+3
    {
        const int c0 = 4 * tid;
        const float4 gv = reinterpret_cast<const float4*>(g)[tid];
        const float4 bv = reinterpret_cast<const float4*>(bt)[tid];
        const float4 dv = reinterpret_cast<const float4*>(dm)[tid];
        ushort4v pk;
        pk[0] = f2bf(((xv[0] - mu) * rstd * gv.x + bv.x) * dv.x);
        pk[1] = f2bf(((xv[1] - mu) * rstd * gv.y + bv.y) * dv.y);
        pk[2] = f2bf(((xv[2] - mu) * rstd * gv.z + bv.z) * dv.z);
        pk[3] = f2bf(((xv[3] - mu) * rstd * gv.w + bv.w) * dv.w);
        reinterpret_cast<ushort4v*>(out + (size_t)row * TWOD)[tid] = pk;
        (void)c0;
    }
    // second half: columns 1024 + 4*tid..
    {
        const float4 gv = reinterpret_cast<const float4*>(g)[256 + tid];
        const float4 bv = reinterpret_cast<const float4*>(bt)[256 + tid];
        const float4 dv = reinterpret_cast<const float4*>(dm)[256 + tid];
        ushort4v pk;
        pk[0] = f2bf(((hv[0] - mu) * rstd * gv.x + bv.x) * dv.x);
        pk[1] = f2bf(((hv[1] - mu) * rstd * gv.y + bv.y) * dv.y);
        pk[2] = f2bf(((hv[2] - mu) * rstd * gv.z + bv.z) * dv.z);
        pk[3] = f2bf(((hv[3] - mu) * rstd * gv.w + bv.w) * dv.w);
        reinterpret_cast<ushort4v*>(out + (size_t)row * TWOD + DDIM)[tid] = pk;
    }
}

// ---------------- bf16 MFMA GEMM, 128x128 tile, BK=32, 4 waves -------------
// A : [16384][2048] bf16 row-major (LN output)
// BT: [N][2048] bf16 row-major (transposed weights)
// EPI 0: gates epilogue. n0<1024 -> r-side: hr = bf16(h * sigmoid(v))
//                        n0>=1024 -> z-side: zbuf[row][col-1024] = sigmoid(v)
// EPI 1: u = tanh(v); out = h*z + (1-z)*u   (zbuf == outp == d_out)
template <int EPI>
__global__ __launch_bounds__(256) void gemm_kernel(const unsigned short* __restrict__ A,
                                                   const unsigned short* __restrict__ BT,
                                                   const float* __restrict__ bias,
                                                   const float* __restrict__ h,
                                                   unsigned short* __restrict__ hr,
                                                   float* zbuf, float* outp) {
    __shared__ unsigned short As[128 * 32];
    __shared__ unsigned short Bs[128 * 32];
    const int tid  = threadIdx.x;
    const int lane = tid & 63;
    const int w    = tid >> 6;      // 0..3
    const int q    = lane >> 4;     // 0..3
    const int r16  = lane & 15;
    const int wr   = (w >> 1) * 64; // wave row offset in tile
    const int wc   = (w & 1) * 64;  // wave col offset in tile
    const size_t m0 = (size_t)blockIdx.x * 128;
    const int    n0 = blockIdx.y * 128;

    f32x4 acc[4][4] = {};

    const unsigned short* Ag = A  + m0 * TWOD;
    const unsigned short* Bg = BT + (size_t)n0 * TWOD;

    for (int k0 = 0; k0 < TWOD; k0 += 32) {
        // stage 8KB A-tile + 8KB B-tile: 512 16B-chunks each, 2 per thread
#pragma unroll
        for (int j = 0; j < 2; ++j) {
            const int c   = w * 128 + j * 64 + lane;
            const int row = c >> 2, cb = c & 3;
            const unsigned short* ga = Ag + (size_t)row * TWOD + k0 + cb * 8;
            const unsigned short* gb = Bg + (size_t)row * TWOD + k0 + cb * 8;
            // LDS dest: wave-uniform base; HW adds lane*16
            char* la = (char*)As + (w * 128 + j * 64) * 16;
            char* lb = (char*)Bs + (w * 128 + j * 64) * 16;
            gload16(ga, la);
            gload16(gb, lb);
        }
        __syncthreads();
        bf16x8 af[4], bfr[4];
#pragma unroll
        for (int m = 0; m < 4; ++m)
            af[m] = *reinterpret_cast<const bf16x8*>(As + (wr + m * 16 + r16) * 32 + q * 8);
#pragma unroll
        for (int n = 0; n < 4; ++n)
            bfr[n] = *reinterpret_cast<const bf16x8*>(Bs + (wc + n * 16 + r16) * 32 + q * 8);
#pragma unroll
        for (int m = 0; m < 4; ++m)
#pragma unroll
            for (int n = 0; n < 4; ++n)
                acc[m][n] = __builtin_amdgcn_mfma_f32_16x16x32_bf16(af[m], bfr[n], acc[m][n], 0, 0, 0);
        __syncthreads();
    }

    // epilogue: D col = lane&15, row = (lane>>4)*4 + reg   [verified m89/m91]
#pragma unroll
    for (int n = 0; n < 4; ++n) {
        const int col = n0 + wc + n * 16 + r16;
        const float bc = bias[EPI == 0 ? col : col];  // gemm2: col<1024
#pragma unroll
        for (int m = 0; m < 4; ++m) {
#pragma unroll
            for (int rg = 0; rg < 4; ++rg) {
                const size_t row = m0 + wr + m * 16 + q * 4 + rg;
                const float v = acc[m][n][rg] + bc;
                if (EPI == 0) {
                    if (n0 < DDIM) {
                        const float rr = 1.0f / (1.0f + __expf(-v));
                        const size_t idx = row * DDIM + col;
                        hr[idx] = f2bf(h[idx] * rr);
                    } else {
                        const float zz = 1.0f / (1.0f + __expf(-v));
                        zbuf[row * DDIM + (col - DDIM)] = zz;
                    }
                } else {
                    const float u = tanhf(v);
                    const size_t idx = row * DDIM + col;
                    const float zz = zbuf[idx];
                    const float hv = h[idx];
                    outp[idx] = hv * zz + (1.0f - zz) * u;
                }
            }
        }
    }
}

// --------------------------------------------------------------------------
extern "C" void kernel_launch(void* const* d_in, const int* in_sizes, int n_in,
                              void* d_out, int out_size, void* d_ws, size_t ws_size,
                              hipStream_t stream) {
    const float* x  = (const float*)d_in[0];
    const float* h  = (const float*)d_in[1];
    const float* Wg = (const float*)d_in[2];
    const float* bg = (const float*)d_in[3];
    const float* Wu = (const float*)d_in[4];
    const float* bu = (const float*)d_in[5];
    const float* g1 = (const float*)d_in[6];
    const float* b1 = (const float*)d_in[7];
    const float* g2 = (const float*)d_in[8];
    const float* b2 = (const float*)d_in[9];
    const float* dm = (const float*)d_in[10];
    float* out = (float*)d_out;

    char* ws = (char*)d_ws;
    unsigned short* WgT = (unsigned short*)(ws);                    // 8 MB
    unsigned short* WuT = (unsigned short*)(ws + 8388608);          // 4 MB
    unsigned short* ln  = (unsigned short*)(ws + 12582912);         // 64 MB
    unsigned short* hr  = (unsigned short*)(ws + 79691776);         // 32 MB

    // 1,2: transpose + cast weights
    wtrans<<<dim3(64, 64), 256, 0, stream>>>(Wg, WgT, TWOD, TWOD);
    wtrans<<<dim3(64, 32), 256, 0, stream>>>(Wu, WuT, TWOD, DDIM);
    // 3: LN1 over concat(x, h)
    ln_kernel<false><<<BATCH, 256, 0, stream>>>(x, (const void*)h, g1, b1, dm, ln);
    // 4: gates GEMM + sigmoid; writes hr (bf16) and z (f32, staged in d_out)
    gemm_kernel<0><<<dim3(128, 16), 256, 0, stream>>>(ln, WgT, bg, h, hr, out, nullptr);
    // 5: LN2 over concat(x, h*r)
    ln_kernel<true><<<BATCH, 256, 0, stream>>>(x, (const void*)hr, g2, b2, dm, ln);
    // 6: u GEMM + tanh + blend; reads z from d_out, overwrites with h_new
    gemm_kernel<1><<<dim3(128, 8), 256, 0, stream>>>(ln, WuT, bu, h, nullptr, out, out);
}

// Round 2
// 460.452 us; speedup vs baseline: 1.1844x; 1.1844x over previous
//
#include <hip/hip_runtime.h>
#include <hip/hip_bf16.h>

// GRUCell fused cell. B=16384, d=1024, 2d=2048.
//   inp  = LN(concat(x,h); g1,b1) * dm
//   gates= inp @ Wg + bg ; r=sig(gates[:, :d]); z=sig(gates[:, d:])
//   inp2 = LN(concat(x, h*r); g2,b2) * dm
//   u    = tanh(inp2 @ Wu + bu)
//   out  = h*z + (1-z)*u
//
// R2: GEMMs moved to 256x256 tile, BK=32, 8-wave, 4-slot LDS ring (128KB),
// 2-phase-per-K-tile schedule with counted vmcnt (never 0 in steady state),
// granule-XOR LDS swizzle (conflict-free ds_read_b128), setprio around MFMA.
//
// ws layout (bytes):
//   [0,            8388608)  WgT  bf16 [2048][2048]  (WgT[n][k] = Wg[k][n])
//   [8388608,     12582912)  WuT  bf16 [1024][2048]
//   [12582912,    79691776)  ln   bf16 [16384][2048] (LN1 then LN2 output)
//   [79691776,   113246208)  hr   bf16 [16384][1024] (h * r)
// z (f32) staged in d_out between GEMM1 and GEMM2 (each element read only by
// the thread that overwrites it in GEMM2's epilogue).

#define BATCH 16384
#define DDIM  1024
#define TWOD  2048
#define LNEPS 1e-5f

#define GBM 256
#define GBN 256
#define GBK 32
#define NTH 512

typedef __bf16 bf16x8 __attribute__((ext_vector_type(8)));
typedef float  f32x4  __attribute__((ext_vector_type(4)));
typedef unsigned short ushort4v __attribute__((ext_vector_type(4)));

__device__ __forceinline__ unsigned short f2bf(float f) {
    unsigned int u = __builtin_bit_cast(unsigned int, f);
    u = (u + 0x7FFFu + ((u >> 16) & 1u)) >> 16;   // round-to-nearest-even
    return (unsigned short)u;
}
__device__ __forceinline__ float bf2f(unsigned short s) {
    unsigned int u = ((unsigned int)s) << 16;
    return __builtin_bit_cast(float, u);
}
__device__ __forceinline__ void gload16(const void* g, void* l) {
    __builtin_amdgcn_global_load_lds((__attribute__((address_space(1))) void*)(g),
                                     (__attribute__((address_space(3))) void*)(l),
                                     16u, 0, 0);
}

// ---------------- weight transpose + f32->bf16 cast ------------------------
__global__ __launch_bounds__(256) void wtrans(const float* __restrict__ W,
                                              unsigned short* __restrict__ WT,
                                              int K, int N) {
    __shared__ float tile[32][33];
    const int k0 = blockIdx.x * 32;
    const int n0 = blockIdx.y * 32;
    const int tx = threadIdx.x & 31;
    const int ty = threadIdx.x >> 5;
#pragma unroll
    for (int p = 0; p < 32; p += 8)
        tile[p + ty][tx] = W[(size_t)(k0 + p + ty) * N + n0 + tx];
    __syncthreads();
#pragma unroll
    for (int p = 0; p < 32; p += 8)
        WT[(size_t)(n0 + p + ty) * K + k0 + tx] = f2bf(tile[tx][p + ty]);
}

// ---------------- fused LayerNorm over concat(x, second) -------------------
template <bool SECOND_BF16>
__global__ __launch_bounds__(256) void ln_kernel(const float* __restrict__ x,
                                                 const void* __restrict__ h2,
                                                 const float* __restrict__ g,
                                                 const float* __restrict__ bt,
                                                 const float* __restrict__ dm,
                                                 unsigned short* __restrict__ out) {
    const int row  = blockIdx.x;
    const int tid  = threadIdx.x;
    const int lane = tid & 63;
    const int w    = tid >> 6;

    const float4 xl = reinterpret_cast<const float4*>(x + (size_t)row * DDIM)[tid];
    float hv[4];
    if (SECOND_BF16) {
        const ushort4v hl = reinterpret_cast<const ushort4v*>(
            (const unsigned short*)h2 + (size_t)row * DDIM)[tid];
#pragma unroll
        for (int j = 0; j < 4; ++j) hv[j] = bf2f(hl[j]);
    } else {
        const float4 hl = reinterpret_cast<const float4*>(
            (const float*)h2 + (size_t)row * DDIM)[tid];
        hv[0] = hl.x; hv[1] = hl.y; hv[2] = hl.z; hv[3] = hl.w;
    }
    float xv[4] = {xl.x, xl.y, xl.z, xl.w};

    float s = 0.f, ss = 0.f;
#pragma unroll
    for (int j = 0; j < 4; ++j) { s += xv[j] + hv[j]; ss += xv[j]*xv[j] + hv[j]*hv[j]; }
#pragma unroll
    for (int o = 32; o; o >>= 1) { s += __shfl_xor(s, o); ss += __shfl_xor(ss, o); }
    __shared__ float red[8];
    if (lane == 0) { red[w] = s; red[4 + w] = ss; }
    __syncthreads();
    s  = red[0] + red[1] + red[2] + red[3];
    ss = red[4] + red[5] + red[6] + red[7];
    const float inv  = 1.0f / (float)TWOD;
    const float mu   = s * inv;
    const float var  = ss * inv - mu * mu;
    const float rstd = rsqrtf(var + LNEPS);

    {
        const float4 gv = reinterpret_cast<const float4*>(g)[tid];
        const float4 bv = reinterpret_cast<const float4*>(bt)[tid];
        const float4 dv = reinterpret_cast<const float4*>(dm)[tid];
        ushort4v pk;
        pk[0] = f2bf(((xv[0] - mu) * rstd * gv.x + bv.x) * dv.x);
        pk[1] = f2bf(((xv[1] - mu) * rstd * gv.y + bv.y) * dv.y);
        pk[2] = f2bf(((xv[2] - mu) * rstd * gv.z + bv.z) * dv.z);
        pk[3] = f2bf(((xv[3] - mu) * rstd * gv.w + bv.w) * dv.w);
        reinterpret_cast<ushort4v*>(out + (size_t)row * TWOD)[tid] = pk;
    }
    {
        const float4 gv = reinterpret_cast<const float4*>(g)[256 + tid];
        const float4 bv = reinterpret_cast<const float4*>(bt)[256 + tid];
        const float4 dv = reinterpret_cast<const float4*>(dm)[256 + tid];
        ushort4v pk;
        pk[0] = f2bf(((hv[0] - mu) * rstd * gv.x + bv.x) * dv.x);
        pk[1] = f2bf(((hv[1] - mu) * rstd * gv.y + bv.y) * dv.y);
        pk[2] = f2bf(((hv[2] - mu) * rstd * gv.z + bv.z) * dv.z);
        pk[3] = f2bf(((hv[3] - mu) * rstd * gv.w + bv.w) * dv.w);
        reinterpret_cast<ushort4v*>(out + (size_t)row * TWOD + DDIM)[tid] = pk;
    }
}

// ---------------- 256x256 8-wave pipelined bf16 GEMM -----------------------
// A : [16384][2048] bf16 row-major (LN output)
// BT: [N][2048]     bf16 row-major (transposed weights)
// LDS: 4-slot ring, slot = 32KB = As[256][32] + Bs[256][32] bf16.
//   Granule = 16B (8 bf16). Row = 4 granules (64B). Swizzle: physical
//   granule = logical ^ ((row>>1)&3)  -> frag ds_read_b128 is 2-way (free).
//   global_load_lds writes LDS linearly; the SOURCE address is pre-swizzled
//   (rule #21: both-sides-or-neither).
// Pipeline: tile T in slot T&3; stage tile T+3 during run T (A in phase 0,
// B in phase 1). Boundary wait vmcnt(8) tolerates tiles T+1,T+2 in flight.
template <int EPI>
__global__ __launch_bounds__(NTH, 2) void gemm8p(const unsigned short* __restrict__ A,
                                                 const unsigned short* __restrict__ BT,
                                                 const float* __restrict__ bias,
                                                 const float* __restrict__ h,
                                                 unsigned short* __restrict__ hr,
                                                 float* __restrict__ zbuf,
                                                 float* __restrict__ outp) {
    extern __shared__ char sm[];      // 131072 bytes
    const int tid  = threadIdx.x;
    const int lane = tid & 63;
    const int w    = tid >> 6;        // 0..7
    const int wm   = w >> 2;          // 0..1 (M-warp)
    const int wn   = w & 3;           // 0..3 (N-warp)
    const int q    = lane >> 4;       // 0..3 (K-chunk)
    const int r16  = lane & 15;
    const size_t m0 = (size_t)blockIdx.x * GBM;
    const int    n0 = blockIdx.y * GBN;

    const unsigned short* Ag = A  + m0 * TWOD;
    const unsigned short* Bg = BT + (size_t)n0 * TWOD;

    // staging: per-thread physical granule -> pre-swizzled global source
    const int G0 = tid, G1 = NTH + tid;
    const int row0 = G0 >> 2, row1 = G1 >> 2;
    const int gl0 = (G0 & 3) ^ ((row0 >> 1) & 3);
    const int gl1 = (G1 & 3) ^ ((row1 >> 1) & 3);
    const unsigned short* a0 = Ag + (size_t)row0 * TWOD + gl0 * 8;
    const unsigned short* a1 = Ag + (size_t)row1 * TWOD + gl1 * 8;
    const unsigned short* b0 = Bg + (size_t)row0 * TWOD + gl0 * 8;
    const unsigned short* b1 = Bg + (size_t)row1 * TWOD + gl1 * 8;
    // LDS dest (wave-uniform base; HW adds lane*16)
    const unsigned dA0 = (unsigned)(w * 64) * 16u;
    const unsigned dA1 = 8192u  + dA0;
    const unsigned dB0 = 16384u + dA0;
    const unsigned dB1 = 24576u + dA0;

#define SLOTB(t) (((unsigned)(t) & 3u) * 32768u)
#define STAGE_A(t) { char* s_ = sm + SLOTB(t); const int k_ = (t) * GBK; \
    gload16(a0 + k_, s_ + dA0); gload16(a1 + k_, s_ + dA1); }
#define STAGE_B(t) { char* s_ = sm + SLOTB(t); const int k_ = (t) * GBK; \
    gload16(b0 + k_, s_ + dB0); gload16(b1 + k_, s_ + dB1); }

    // frag-read byte offsets: phys granule = q ^ ((r16>>1)&3) (row-parity
    // trick: (row>>1)&3 == (r16>>1)&3 since row = 16*a + r16)
    const unsigned pgo = (unsigned)((q ^ ((r16 >> 1) & 3)) * 16);
    const unsigned ard = (unsigned)((wm * 128 + r16) * 64) + pgo;
    const unsigned brd = 16384u + (unsigned)((wn * 64 + r16) * 64) + pgo;

    f32x4 acc[8][4] = {};
    const int NT = TWOD / GBK;   // 64

    // prologue: tiles 0,1,2 in flight (12 loads/thread)
    STAGE_A(0); STAGE_B(0); STAGE_A(1); STAGE_B(1); STAGE_A(2); STAGE_B(2);

    for (int T = 0; T < NT; ++T) {
        // boundary: confirm tile T landed (tolerate newer tiles in flight)
        if (T < NT - 2)       { asm volatile("s_waitcnt vmcnt(8)" ::: "memory"); }
        else if (T == NT - 2) { asm volatile("s_waitcnt vmcnt(4)" ::: "memory"); }
        else                  { asm volatile("s_waitcnt vmcnt(0)" ::: "memory"); }
        __builtin_amdgcn_s_barrier();
        const unsigned sb = SLOTB(T);
        bf16x8 af[4], bf[4];
        // ---- phase 0: quadrant mh=0 ----
#pragma unroll
        for (int n = 0; n < 4; ++n)
            bf[n] = *(const bf16x8*)(sm + sb + brd + (unsigned)n * 1024u);
#pragma unroll
        for (int i = 0; i < 4; ++i)
            af[i] = *(const bf16x8*)(sm + sb + ard + (unsigned)i * 1024u);
        if (T + 3 < NT) STAGE_A(T + 3);
        __builtin_amdgcn_s_barrier();
        asm volatile("s_waitcnt lgkmcnt(0)" ::: "memory");
        __builtin_amdgcn_sched_barrier(0);
        __builtin_amdgcn_s_setprio(1);
#pragma unroll
        for (int i = 0; i < 4; ++i)
#pragma unroll
            for (int n = 0; n < 4; ++n)
                acc[i][n] = __builtin_amdgcn_mfma_f32_16x16x32_bf16(af[i], bf[n], acc[i][n], 0, 0, 0);
        __builtin_amdgcn_s_setprio(0);
        __builtin_amdgcn_s_barrier();
        // ---- phase 1: quadrant mh=1 ----
#pragma unroll
        for (int i = 0; i < 4; ++i)
            af[i] = *(const bf16x8*)(sm + sb + ard + (unsigned)(4 + i) * 1024u);
        if (T + 3 < NT) STAGE_B(T + 3);
        __builtin_amdgcn_s_barrier();
        asm volatile("s_waitcnt lgkmcnt(0)" ::: "memory");
        __builtin_amdgcn_sched_barrier(0);
        __builtin_amdgcn_s_setprio(1);
#pragma unroll
        for (int i = 0; i < 4; ++i)
#pragma unroll
            for (int n = 0; n < 4; ++n)
                acc[4 + i][n] = __builtin_amdgcn_mfma_f32_16x16x32_bf16(af[i], bf[n], acc[4 + i][n], 0, 0, 0);
        __builtin_amdgcn_s_setprio(0);
        // next iteration's [vmcnt; s_barrier] closes this phase
    }

    // epilogue: D col = lane&15, row = (lane>>4)*4 + reg  [verified m89/m91]
#pragma unroll
    for (int n = 0; n < 4; ++n) {
        const int col = n0 + wn * 64 + n * 16 + r16;
        const float bc = bias[col];
#pragma unroll
        for (int m = 0; m < 8; ++m) {
#pragma unroll
            for (int rg = 0; rg < 4; ++rg) {
                const size_t row = m0 + wm * 128 + m * 16 + q * 4 + rg;
                const float v = acc[m][n][rg] + bc;
                if (EPI == 0) {
                    if (n0 < DDIM) {
                        const float rr = 1.0f / (1.0f + __expf(-v));
                        const size_t idx = row * DDIM + col;
                        hr[idx] = f2bf(h[idx] * rr);
                    } else {
                        const float zz = 1.0f / (1.0f + __expf(-v));
                        zbuf[row * DDIM + (col - DDIM)] = zz;
                    }
                } else {
                    const float u = tanhf(v);
                    const size_t idx = row * DDIM + col;
                    const float zz = zbuf[idx];
                    const float hv = h[idx];
                    outp[idx] = hv * zz + (1.0f - zz) * u;
                }
            }
        }
    }
#undef SLOTB
#undef STAGE_A
#undef STAGE_B
}

// --------------------------------------------------------------------------
extern "C" void kernel_launch(void* const* d_in, const int* in_sizes, int n_in,
                              void* d_out, int out_size, void* d_ws, size_t ws_size,
                              hipStream_t stream) {
    const float* x  = (const float*)d_in[0];
    const float* h  = (const float*)d_in[1];
    const float* Wg = (const float*)d_in[2];
    const float* bg = (const float*)d_in[3];
    const float* Wu = (const float*)d_in[4];
    const float* bu = (const float*)d_in[5];
    const float* g1 = (const float*)d_in[6];
    const float* b1 = (const float*)d_in[7];
    const float* g2 = (const float*)d_in[8];
    const float* b2 = (const float*)d_in[9];
    const float* dm = (const float*)d_in[10];
    float* out = (float*)d_out;

    char* ws = (char*)d_ws;
    unsigned short* WgT = (unsigned short*)(ws);                    // 8 MB
    unsigned short* WuT = (unsigned short*)(ws + 8388608);          // 4 MB
    unsigned short* ln  = (unsigned short*)(ws + 12582912);         // 64 MB
    unsigned short* hr  = (unsigned short*)(ws + 79691776);         // 32 MB

    // allow 128KB dynamic LDS (host-side attr, graph-capture safe)
    hipFuncSetAttribute((const void*)gemm8p<0>,
                        hipFuncAttributeMaxDynamicSharedMemorySize, 131072);
    hipFuncSetAttribute((const void*)gemm8p<1>,
                        hipFuncAttributeMaxDynamicSharedMemorySize, 131072);

    wtrans<<<dim3(64, 64), 256, 0, stream>>>(Wg, WgT, TWOD, TWOD);
    wtrans<<<dim3(64, 32), 256, 0, stream>>>(Wu, WuT, TWOD, DDIM);
    ln_kernel<false><<<BATCH, 256, 0, stream>>>(x, (const void*)h, g1, b1, dm, ln);
    gemm8p<0><<<dim3(64, 8), NTH, 131072, stream>>>(ln, WgT, bg, h, hr, out, nullptr);
    ln_kernel<true><<<BATCH, 256, 0, stream>>>(x, (const void*)hr, g2, b2, dm, ln);
    gemm8p<1><<<dim3(64, 4), NTH, 131072, stream>>>(ln, WuT, bu, h, nullptr, out, out);
}

// Round 3
// 454.046 us; speedup vs baseline: 1.2011x; 1.0141x over previous
//
#include <hip/hip_runtime.h>
#include <hip/hip_bf16.h>

// GRUCell fused cell. B=16384, d=1024, 2d=2048.
//   inp  = LN(concat(x,h); g1,b1) * dm
//   gates= inp @ Wg + bg ; r=sig(gates[:, :d]); z=sig(gates[:, d:])
//   inp2 = LN(concat(x, h*r); g2,b2) * dm
//   u    = tanh(inp2 @ Wu + bu)
//   out  = h*z + (1-z)*u
//
// R3: same 256x256 / 4-slot-ring / counted-vmcnt GEMM as R2, but intra-tile
// sync walls removed: no per-phase barriers, no inline lgkmcnt(0), no
// sched_barrier. The compiler's fine-grained lgkmcnt scheduling overlaps
// ds_read service with MFMA issue (R2's walls serialized them -> 597 TF,
// the known 2-phase ceiling). One {vmcnt(counted); s_barrier} per K-tile.
//
// ws layout (bytes):
//   [0,            8388608)  WgT  bf16 [2048][2048]  (WgT[n][k] = Wg[k][n])
//   [8388608,     12582912)  WuT  bf16 [1024][2048]
//   [12582912,    79691776)  ln   bf16 [16384][2048] (LN1 then LN2 output)
//   [79691776,   113246208)  hr   bf16 [16384][1024] (h * r)
// z (f32) staged in d_out between GEMM1 and GEMM2 (each element read only by
// the thread that overwrites it in GEMM2's epilogue).

#define BATCH 16384
#define DDIM  1024
#define TWOD  2048
#define LNEPS 1e-5f

#define GBM 256
#define GBN 256
#define GBK 32
#define NTH 512

typedef __bf16 bf16x8 __attribute__((ext_vector_type(8)));
typedef float  f32x4  __attribute__((ext_vector_type(4)));
typedef unsigned short ushort4v __attribute__((ext_vector_type(4)));

__device__ __forceinline__ unsigned short f2bf(float f) {
    unsigned int u = __builtin_bit_cast(unsigned int, f);
    u = (u + 0x7FFFu + ((u >> 16) & 1u)) >> 16;   // round-to-nearest-even
    return (unsigned short)u;
}
__device__ __forceinline__ float bf2f(unsigned short s) {
    unsigned int u = ((unsigned int)s) << 16;
    return __builtin_bit_cast(float, u);
}
__device__ __forceinline__ void gload16(const void* g, void* l) {
    __builtin_amdgcn_global_load_lds((__attribute__((address_space(1))) void*)(g),
                                     (__attribute__((address_space(3))) void*)(l),
                                     16u, 0, 0);
}

// ---------------- weight transpose + f32->bf16 cast ------------------------
__global__ __launch_bounds__(256) void wtrans(const float* __restrict__ W,
                                              unsigned short* __restrict__ WT,
                                              int K, int N) {
    __shared__ float tile[32][33];
    const int k0 = blockIdx.x * 32;
    const int n0 = blockIdx.y * 32;
    const int tx = threadIdx.x & 31;
    const int ty = threadIdx.x >> 5;
#pragma unroll
    for (int p = 0; p < 32; p += 8)
        tile[p + ty][tx] = W[(size_t)(k0 + p + ty) * N + n0 + tx];
    __syncthreads();
#pragma unroll
    for (int p = 0; p < 32; p += 8)
        WT[(size_t)(n0 + p + ty) * K + k0 + tx] = f2bf(tile[tx][p + ty]);
}

// ---------------- fused LayerNorm over concat(x, second) -------------------
template <bool SECOND_BF16>
__global__ __launch_bounds__(256) void ln_kernel(const float* __restrict__ x,
                                                 const void* __restrict__ h2,
                                                 const float* __restrict__ g,
                                                 const float* __restrict__ bt,
                                                 const float* __restrict__ dm,
                                                 unsigned short* __restrict__ out) {
    const int row  = blockIdx.x;
    const int tid  = threadIdx.x;
    const int lane = tid & 63;
    const int w    = tid >> 6;

    const float4 xl = reinterpret_cast<const float4*>(x + (size_t)row * DDIM)[tid];
    float hv[4];
    if (SECOND_BF16) {
        const ushort4v hl = reinterpret_cast<const ushort4v*>(
            (const unsigned short*)h2 + (size_t)row * DDIM)[tid];
#pragma unroll
        for (int j = 0; j < 4; ++j) hv[j] = bf2f(hl[j]);
    } else {
        const float4 hl = reinterpret_cast<const float4*>(
            (const float*)h2 + (size_t)row * DDIM)[tid];
        hv[0] = hl.x; hv[1] = hl.y; hv[2] = hl.z; hv[3] = hl.w;
    }
    float xv[4] = {xl.x, xl.y, xl.z, xl.w};

    float s = 0.f, ss = 0.f;
#pragma unroll
    for (int j = 0; j < 4; ++j) { s += xv[j] + hv[j]; ss += xv[j]*xv[j] + hv[j]*hv[j]; }
#pragma unroll
    for (int o = 32; o; o >>= 1) { s += __shfl_xor(s, o); ss += __shfl_xor(ss, o); }
    __shared__ float red[8];
    if (lane == 0) { red[w] = s; red[4 + w] = ss; }
    __syncthreads();
    s  = red[0] + red[1] + red[2] + red[3];
    ss = red[4] + red[5] + red[6] + red[7];
    const float inv  = 1.0f / (float)TWOD;
    const float mu   = s * inv;
    const float var  = ss * inv - mu * mu;
    const float rstd = rsqrtf(var + LNEPS);

    {
        const float4 gv = reinterpret_cast<const float4*>(g)[tid];
        const float4 bv = reinterpret_cast<const float4*>(bt)[tid];
        const float4 dv = reinterpret_cast<const float4*>(dm)[tid];
        ushort4v pk;
        pk[0] = f2bf(((xv[0] - mu) * rstd * gv.x + bv.x) * dv.x);
        pk[1] = f2bf(((xv[1] - mu) * rstd * gv.y + bv.y) * dv.y);
        pk[2] = f2bf(((xv[2] - mu) * rstd * gv.z + bv.z) * dv.z);
        pk[3] = f2bf(((xv[3] - mu) * rstd * gv.w + bv.w) * dv.w);
        reinterpret_cast<ushort4v*>(out + (size_t)row * TWOD)[tid] = pk;
    }
    {
        const float4 gv = reinterpret_cast<const float4*>(g)[256 + tid];
        const float4 bv = reinterpret_cast<const float4*>(bt)[256 + tid];
        const float4 dv = reinterpret_cast<const float4*>(dm)[256 + tid];
        ushort4v pk;
        pk[0] = f2bf(((hv[0] - mu) * rstd * gv.x + bv.x) * dv.x);
        pk[1] = f2bf(((hv[1] - mu) * rstd * gv.y + bv.y) * dv.y);
        pk[2] = f2bf(((hv[2] - mu) * rstd * gv.z + bv.z) * dv.z);
        pk[3] = f2bf(((hv[3] - mu) * rstd * gv.w + bv.w) * dv.w);
        reinterpret_cast<ushort4v*>(out + (size_t)row * TWOD + DDIM)[tid] = pk;
    }
}

// ---------------- 256x256 8-wave pipelined bf16 GEMM -----------------------
// A : [16384][2048] bf16 row-major (LN output)
// BT: [N][2048]     bf16 row-major (transposed weights)
// LDS: 4-slot ring, slot = 32KB = As[256][32] + Bs[256][32] bf16.
//   Granule = 16B (8 bf16). Row = 4 granules (64B). Swizzle: physical
//   granule = logical ^ ((row>>1)&3)  -> frag ds_read_b128 is 2-way (free,
//   PMC-verified 0 conflicts in R2).
//   global_load_lds writes LDS linearly; the SOURCE address is pre-swizzled
//   (rule #21: both-sides-or-neither).
// Pipeline: tile T in slot T&3; stage tile T+3 during tile T. One sync point
// per K-tile: counted vmcnt (8 steady / 4 / 0 taper) + raw s_barrier, both
// with compiler memory clobber only (no HW waitcnt drain, no sched walls).
// Ring safety: barrier-per-tile bounds wave skew <1 tile; stage(T+3) writes
// the slot of tile T-1, which all waves finished before passing barrier T.
template <int EPI>
__global__ __launch_bounds__(NTH, 2) void gemm8p(const unsigned short* __restrict__ A,
                                                 const unsigned short* __restrict__ BT,
                                                 const float* __restrict__ bias,
                                                 const float* __restrict__ h,
                                                 unsigned short* __restrict__ hr,
                                                 float* __restrict__ zbuf,
                                                 float* __restrict__ outp) {
    extern __shared__ char sm[];      // 131072 bytes
    const int tid  = threadIdx.x;
    const int lane = tid & 63;
    const int w    = tid >> 6;        // 0..7
    const int wm   = w >> 2;          // 0..1 (M-warp)
    const int wn   = w & 3;           // 0..3 (N-warp)
    const int q    = lane >> 4;       // 0..3 (K-chunk)
    const int r16  = lane & 15;
    const size_t m0 = (size_t)blockIdx.x * GBM;
    const int    n0 = blockIdx.y * GBN;

    const unsigned short* Ag = A  + m0 * TWOD;
    const unsigned short* Bg = BT + (size_t)n0 * TWOD;

    // staging: per-thread physical granule -> pre-swizzled global source
    const int G0 = tid, G1 = NTH + tid;
    const int row0 = G0 >> 2, row1 = G1 >> 2;
    const int gl0 = (G0 & 3) ^ ((row0 >> 1) & 3);
    const int gl1 = (G1 & 3) ^ ((row1 >> 1) & 3);
    const unsigned short* a0 = Ag + (size_t)row0 * TWOD + gl0 * 8;
    const unsigned short* a1 = Ag + (size_t)row1 * TWOD + gl1 * 8;
    const unsigned short* b0 = Bg + (size_t)row0 * TWOD + gl0 * 8;
    const unsigned short* b1 = Bg + (size_t)row1 * TWOD + gl1 * 8;
    // LDS dest (wave-uniform base; HW adds lane*16)
    const unsigned dA0 = (unsigned)(w * 64) * 16u;
    const unsigned dA1 = 8192u  + dA0;
    const unsigned dB0 = 16384u + dA0;
    const unsigned dB1 = 24576u + dA0;

#define SLOTB(t) (((unsigned)(t) & 3u) * 32768u)
#define STAGE_A(t) { char* s_ = sm + SLOTB(t); const int k_ = (t) * GBK; \
    gload16(a0 + k_, s_ + dA0); gload16(a1 + k_, s_ + dA1); }
#define STAGE_B(t) { char* s_ = sm + SLOTB(t); const int k_ = (t) * GBK; \
    gload16(b0 + k_, s_ + dB0); gload16(b1 + k_, s_ + dB1); }

    // frag-read byte offsets: phys granule = q ^ ((r16>>1)&3) (row-parity
    // trick: (row>>1)&3 == (r16>>1)&3 since row = 16*m + r16)
    const unsigned pgo = (unsigned)((q ^ ((r16 >> 1) & 3)) * 16);
    const unsigned ard = (unsigned)((wm * 128 + r16) * 64) + pgo;
    const unsigned brd = 16384u + (unsigned)((wn * 64 + r16) * 64) + pgo;

    f32x4 acc[8][4] = {};
    const int NT = TWOD / GBK;   // 64

    // prologue: tiles 0,1,2 in flight (12 vm-instructions per wave)
    STAGE_A(0); STAGE_B(0); STAGE_A(1); STAGE_B(1); STAGE_A(2); STAGE_B(2);

    for (int T = 0; T < NT; ++T) {
        // boundary: confirm tile T landed (tolerate newer tiles in flight);
        // compiler memory clobber only - no lgkm drain, no sched wall.
        if (T < NT - 2)       { asm volatile("s_waitcnt vmcnt(8)" ::: "memory"); }
        else if (T == NT - 2) { asm volatile("s_waitcnt vmcnt(4)" ::: "memory"); }
        else                  { asm volatile("s_waitcnt vmcnt(0)" ::: "memory"); }
        asm volatile("s_barrier" ::: "memory");

        const unsigned sb = SLOTB(T);
        bf16x8 af0[4], af1[4], bf[4];
#pragma unroll
        for (int n = 0; n < 4; ++n)
            bf[n] = *(const bf16x8*)(sm + sb + brd + (unsigned)n * 1024u);
#pragma unroll
        for (int i = 0; i < 4; ++i)
            af0[i] = *(const bf16x8*)(sm + sb + ard + (unsigned)i * 1024u);
        if (T + 3 < NT) STAGE_A(T + 3);
        __builtin_amdgcn_s_setprio(1);
#pragma unroll
        for (int i = 0; i < 4; ++i)
#pragma unroll
            for (int n = 0; n < 4; ++n)
                acc[i][n] = __builtin_amdgcn_mfma_f32_16x16x32_bf16(af0[i], bf[n], acc[i][n], 0, 0, 0);
        __builtin_amdgcn_s_setprio(0);
#pragma unroll
        for (int i = 0; i < 4; ++i)
            af1[i] = *(const bf16x8*)(sm + sb + ard + (unsigned)(4 + i) * 1024u);
        if (T + 3 < NT) STAGE_B(T + 3);
        __builtin_amdgcn_s_setprio(1);
#pragma unroll
        for (int i = 0; i < 4; ++i)
#pragma unroll
            for (int n = 0; n < 4; ++n)
                acc[4 + i][n] = __builtin_amdgcn_mfma_f32_16x16x32_bf16(af1[i], bf[n], acc[4 + i][n], 0, 0, 0);
        __builtin_amdgcn_s_setprio(0);
    }

    // epilogue: D col = lane&15, row = (lane>>4)*4 + reg  [verified m89/m91]
#pragma unroll
    for (int n = 0; n < 4; ++n) {
        const int col = n0 + wn * 64 + n * 16 + r16;
        const float bc = bias[col];
#pragma unroll
        for (int m = 0; m < 8; ++m) {
#pragma unroll
            for (int rg = 0; rg < 4; ++rg) {
                const size_t row = m0 + wm * 128 + m * 16 + q * 4 + rg;
                const float v = acc[m][n][rg] + bc;
                if (EPI == 0) {
                    if (n0 < DDIM) {
                        const float rr = 1.0f / (1.0f + __expf(-v));
                        const size_t idx = row * DDIM + col;
                        hr[idx] = f2bf(h[idx] * rr);
                    } else {
                        const float zz = 1.0f / (1.0f + __expf(-v));
                        zbuf[row * DDIM + (col - DDIM)] = zz;
                    }
                } else {
                    const float u = tanhf(v);
                    const size_t idx = row * DDIM + col;
                    const float zz = zbuf[idx];
                    const float hv = h[idx];
                    outp[idx] = hv * zz + (1.0f - zz) * u;
                }
            }
        }
    }
#undef SLOTB
#undef STAGE_A
#undef STAGE_B
}

// --------------------------------------------------------------------------
extern "C" void kernel_launch(void* const* d_in, const int* in_sizes, int n_in,
                              void* d_out, int out_size, void* d_ws, size_t ws_size,
                              hipStream_t stream) {
    const float* x  = (const float*)d_in[0];
    const float* h  = (const float*)d_in[1];
    const float* Wg = (const float*)d_in[2];
    const float* bg = (const float*)d_in[3];
    const float* Wu = (const float*)d_in[4];
    const float* bu = (const float*)d_in[5];
    const float* g1 = (const float*)d_in[6];
    const float* b1 = (const float*)d_in[7];
    const float* g2 = (const float*)d_in[8];
    const float* b2 = (const float*)d_in[9];
    const float* dm = (const float*)d_in[10];
    float* out = (float*)d_out;

    char* ws = (char*)d_ws;
    unsigned short* WgT = (unsigned short*)(ws);                    // 8 MB
    unsigned short* WuT = (unsigned short*)(ws + 8388608);          // 4 MB
    unsigned short* ln  = (unsigned short*)(ws + 12582912);         // 64 MB
    unsigned short* hr  = (unsigned short*)(ws + 79691776);         // 32 MB

    // allow 128KB dynamic LDS (host-side attr, graph-capture safe)
    hipFuncSetAttribute((const void*)gemm8p<0>,
                        hipFuncAttributeMaxDynamicSharedMemorySize, 131072);
    hipFuncSetAttribute((const void*)gemm8p<1>,
                        hipFuncAttributeMaxDynamicSharedMemorySize, 131072);

    wtrans<<<dim3(64, 64), 256, 0, stream>>>(Wg, WgT, TWOD, TWOD);
    wtrans<<<dim3(64, 32), 256, 0, stream>>>(Wu, WuT, TWOD, DDIM);
    ln_kernel<false><<<BATCH, 256, 0, stream>>>(x, (const void*)h, g1, b1, dm, ln);
    gemm8p<0><<<dim3(64, 8), NTH, 131072, stream>>>(ln, WgT, bg, h, hr, out, nullptr);
    ln_kernel<true><<<BATCH, 256, 0, stream>>>(x, (const void*)hr, g2, b2, dm, ln);
    gemm8p<1><<<dim3(64, 4), NTH, 131072, stream>>>(ln, WuT, bu, h, nullptr, out, out);
}